// Round 7
// baseline (233.740 us; speedup 1.0000x reference)
//
#include <hip/hip_runtime.h>
#include <hip/hip_cooperative_groups.h>
#include <math.h>

namespace cg = cooperative_groups;

// Problem constants (match reference setup_inputs)
#define BATCH   512
#define FEATS   30
#define NNZT    (BATCH * FEATS)       // 15360 per half
#define FT_OUT  512
#define NFEAT   40960
#define NVFEAT  640

// 64x64 transpose tiles; fused kernel: 512 blocks x 512 threads,
// each half-block (256 thr) transposes one tile per pair-iteration.
#define FT_TILES  ((FT_OUT / 64) * (NFEAT / 64))    // 5120
#define FFT_TILES ((FT_OUT / 64) * (NVFEAT / 64))   // 80
#define NTILES    (FT_TILES + FFT_TILES)            // 5200
#define NPAIRS    (NTILES / 2)                      // 2600

// pack two f32 into one u32 of 2 bf16 (RNE)
__device__ inline unsigned int bpack(float a, float b) {
    unsigned int ua = __float_as_uint(a), ub = __float_as_uint(b);
    ua = (ua + 0x7fff + ((ua >> 16) & 1)) >> 16;
    ub = (ub + 0x7fff + ((ub >> 16) & 1)) >> 16;
    return ua | (ub << 16);
}
__device__ inline float bf2f(unsigned int u) {        // low 16 bits -> f32
    return __uint_as_float(u << 16);
}
__device__ inline float bf2f_hi(unsigned int u) {     // high 16 bits -> f32
    return __uint_as_float(u & 0xffff0000u);
}

// ---------------------------------------------------------------------------
// Fused: phase 1 = transpose+pack (grid-stride, proven R6 tile code),
//        grid.sync(),
//        phase 2 = gather+finalize (proven R5 code, block per batch row).
// LDS overlay: phase-1 tiles (2 x 64 x 65 f32 = 33.3 KB) ⊇ phase-2 pacc
// (8 x 2 x 512 f32 = 32 KB). 4 blocks/CU -> 1024 co-resident >= 512 grid.
__global__ __launch_bounds__(512) void halfkp_fused(
    unsigned short* __restrict__ ftT,   // ws: [NFEAT][FT_OUT] bf16
    unsigned short* __restrict__ fftT,  // ws: [NVFEAT][FT_OUT] bf16
    const int*   __restrict__ stm_idx,  // [2][NNZT]
    const int*   __restrict__ nstm_idx,
    const float* __restrict__ values,   // [NNZT]
    const float* __restrict__ ft_w,     // [FT_OUT][NFEAT]
    const float* __restrict__ fft_w,    // [FT_OUT][NVFEAT]
    const float* __restrict__ ft_b, const float* __restrict__ fft_b,
    const float* __restrict__ out_w, const float* __restrict__ out_b,
    float*       __restrict__ out)
{
    __shared__ float smem[2 * 64 * 65];   // 33.28 KB, overlaid across phases
    __shared__ int   cs[2][FEATS];
    __shared__ float vs[FEATS];
    __shared__ float red[8];

    const int tid  = threadIdx.x;
    const int half = tid >> 8;            // 0/1: which tile of the pair
    const int htid = tid & 255;
    const int wid4 = htid >> 6;           // wave within half (0..3)
    const int lane = tid & 63;

    // ---------------- phase 1: transpose + pack ----------------
    float (*tileh)[65] = (float (*)[65])(smem + half * 64 * 65);

    for (int p = blockIdx.x; p < NPAIRS; p += gridDim.x) {
        const int t = 2 * p + half;       // < NTILES always (NTILES even)

        const float* W; unsigned short* T; int C, fb, cb;
        if (t < FT_TILES) {
            W = ft_w;  T = ftT;  C = NFEAT;
            fb = (t & 7) * 64;  cb = (t >> 3) * 64;
        } else {
            int u = t - FT_TILES;
            W = fft_w; T = fftT; C = NVFEAT;
            fb = (u & 7) * 64;  cb = (u >> 3) * 64;
        }

        // read 64 f-rows x 64 c (256B contiguous per 16-lane group)
#pragma unroll
        for (int it = 0; it < 4; ++it) {
            const int row = it * 16 + wid4 * 4 + (lane >> 4);   // 0..63
            const int cq  = (lane & 15) * 4;
            const float4 v = *(const float4*)(W + (size_t)(fb + row) * C + cb + cq);
            tileh[cq + 0][row] = v.x;
            tileh[cq + 1][row] = v.y;
            tileh[cq + 2][row] = v.z;
            tileh[cq + 3][row] = v.w;
        }
        __syncthreads();   // both halves share the same p -> uniform

        // write 64 c-rows x 64 f bf16 (full 128B line per c-row)
#pragma unroll
        for (int it = 0; it < 2; ++it) {
            const int c  = it * 32 + (htid >> 3);               // 0..63
            const int f0 = (htid & 7) * 8;
            uint4 o;
            unsigned int* op = (unsigned int*)&o;
#pragma unroll
            for (int j = 0; j < 4; ++j)
                op[j] = bpack(tileh[c][f0 + 2 * j], tileh[c][f0 + 2 * j + 1]);
            *(uint4*)(T + (size_t)(cb + c) * FT_OUT + fb + f0) = o;
        }
        __syncthreads();   // protect tile before next iteration's overwrite
    }

    cg::this_grid().sync();

    // ---------------- phase 2: gather + finalize ----------------
    float (*pacc)[2][FT_OUT] = (float (*)[2][FT_OUT])smem;   // 32 KB overlay

    const int b   = blockIdx.x;
    const int wid = tid >> 6;

    if (tid < FEATS)
        cs[0][tid] = stm_idx[NNZT + b * FEATS + tid];
    else if (tid < 2 * FEATS)
        cs[1][tid - FEATS] = nstm_idx[NNZT + b * FEATS + (tid - FEATS)];
    else if (tid < 3 * FEATS)
        vs[tid - 2 * FEATS] = values[b * FEATS + (tid - 2 * FEATS)];
    __syncthreads();

    const int f0 = lane * 8;
    float a0[8], a1[8];
#pragma unroll
    for (int i = 0; i < 8; ++i) { a0[i] = 0.0f; a1[i] = 0.0f; }

    // 120 virtual entries: k = h*60 + j; j<30 -> ftT[c], j>=30 -> fftT[c%640]
    for (int k = wid; k < 4 * FEATS; k += 8) {
        const int h = k >= 2 * FEATS;
        const int j = k - h * 2 * FEATS;          // 0..59
        const int jj = (j >= FEATS) ? j - FEATS : j;
        const int c = cs[h][jj];
        const float v = vs[jj];
        const unsigned short* rowp = (j >= FEATS)
            ? fftT + (size_t)(c % NVFEAT) * FT_OUT
            : ftT  + (size_t)c * FT_OUT;
        const uint4 r = *(const uint4*)(rowp + f0);
        const unsigned int* rw = (const unsigned int*)&r;
        float* acc = h ? a1 : a0;
#pragma unroll
        for (int q = 0; q < 4; ++q) {
            acc[2 * q]     += bf2f(rw[q]) * v;
            acc[2 * q + 1] += bf2f_hi(rw[q]) * v;
        }
    }

#pragma unroll
    for (int i = 0; i < 8; i += 4) {
        *(float4*)&pacc[wid][0][f0 + i] = make_float4(a0[i], a0[i+1], a0[i+2], a0[i+3]);
        *(float4*)&pacc[wid][1][f0 + i] = make_float4(a1[i], a1[i+1], a1[i+2], a1[i+3]);
    }
    __syncthreads();

    const int f = tid;
    float s0 = 0.0f, s1 = 0.0f;
#pragma unroll
    for (int w = 0; w < 8; ++w) { s0 += pacc[w][0][f]; s1 += pacc[w][1][f]; }

    const float bias = ft_b[f] + fft_b[f];
    const float h0 = fminf(fmaxf(s0 + bias, 0.0f), 1.0f);
    const float h1 = fminf(fmaxf(s1 + bias, 0.0f), 1.0f);

    float total = h0 * out_w[f] + h1 * out_w[FT_OUT + f];
#pragma unroll
    for (int off = 32; off > 0; off >>= 1)
        total += __shfl_down(total, off, 64);
    if (lane == 0) red[wid] = total;
    __syncthreads();
    if (tid == 0) {
        float s = red[0];
#pragma unroll
        for (int w = 1; w < 8; ++w) s += red[w];
        s += out_b[0];
        out[b] = 1.0f / (1.0f + expf(-s));
    }
}

// ---------------------------------------------------------------------------
// Fallback (ws too small): proven round-1 direct kernel (slow but correct).
__global__ __launch_bounds__(512) void halfkp_direct(
    const int* __restrict__ stm_idx, const int* __restrict__ nstm_idx,
    const float* __restrict__ values,
    const float* __restrict__ ft_w, const float* __restrict__ ft_b,
    const float* __restrict__ fft_w, const float* __restrict__ fft_b,
    const float* __restrict__ out_w, const float* __restrict__ out_b,
    float* __restrict__ out)
{
    const int b = blockIdx.x;
    const int f = threadIdx.x;
    const float bias = ft_b[f] + fft_b[f];
    const float* ftrow  = ft_w  + (size_t)f * NFEAT;
    const float* fftrow = fft_w + f * NVFEAT;
    float acc0 = bias, acc1 = bias;
    for (int k = 0; k < FEATS; ++k) {
        int j = b * FEATS + k;
        int c0 = stm_idx[NNZT + j], c1 = nstm_idx[NNZT + j];
        float v = values[j];
        acc0 += (ftrow[c0] + fftrow[c0 % NVFEAT]) * v;
        acc1 += (ftrow[c1] + fftrow[c1 % NVFEAT]) * v;
    }
    const float h0 = fminf(fmaxf(acc0, 0.0f), 1.0f);
    const float h1 = fminf(fmaxf(acc1, 0.0f), 1.0f);
    float total = h0 * out_w[f] + h1 * out_w[FT_OUT + f];
#pragma unroll
    for (int off = 32; off > 0; off >>= 1)
        total += __shfl_down(total, off, 64);
    __shared__ float red[8];
    if ((threadIdx.x & 63) == 0) red[threadIdx.x >> 6] = total;
    __syncthreads();
    if (threadIdx.x == 0) {
        float s = red[0];
#pragma unroll
        for (int w = 1; w < 8; ++w) s += red[w];
        out[b] = 1.0f / (1.0f + expf(-(s + out_b[0])));
    }
}

// ---------------------------------------------------------------------------
extern "C" void kernel_launch(void* const* d_in, const int* in_sizes, int n_in,
                              void* d_out, int out_size, void* d_ws, size_t ws_size,
                              hipStream_t stream)
{
    const int*   stm_idx  = (const int*)  d_in[0];
    const int*   nstm_idx = (const int*)  d_in[1];
    const float* values   = (const float*)d_in[2];
    const float* ft_w     = (const float*)d_in[3];
    const float* ft_b     = (const float*)d_in[4];
    const float* fft_w    = (const float*)d_in[5];
    const float* fft_b    = (const float*)d_in[6];
    const float* out_w    = (const float*)d_in[7];
    const float* out_b    = (const float*)d_in[8];
    float*       out      = (float*)d_out;

    const size_t ftT_bytes  = (size_t)NFEAT  * FT_OUT * 2;
    const size_t fftT_bytes = (size_t)NVFEAT * FT_OUT * 2;

    if (ws_size >= ftT_bytes + fftT_bytes) {
        unsigned short* ftT  = (unsigned short*)d_ws;
        unsigned short* fftT = (unsigned short*)((char*)d_ws + ftT_bytes);

        void* args[] = {
            (void*)&ftT, (void*)&fftT,
            (void*)&stm_idx, (void*)&nstm_idx, (void*)&values,
            (void*)&ft_w, (void*)&fft_w,
            (void*)&ft_b, (void*)&fft_b,
            (void*)&out_w, (void*)&out_b, (void*)&out
        };
        hipLaunchCooperativeKernel((const void*)halfkp_fused,
                                   dim3(BATCH), dim3(512), args, 0, stream);
    } else {
        halfkp_direct<<<BATCH, 512, 0, stream>>>(stm_idx, nstm_idx, values,
                                                 ft_w, ft_b, fft_w, fft_b,
                                                 out_w, out_b, out);
    }
}

// Round 9
// 150.044 us; speedup vs baseline: 1.5578x; 1.5578x over previous
//
#include <hip/hip_runtime.h>
#include <math.h>

// Problem constants (match reference setup_inputs)
#define BATCH   512
#define FEATS   30
#define NNZT    (BATCH * FEATS)       // 15360 per half
#define FT_OUT  512
#define NFEAT   40960
#define NVFEAT  640

// 64x64 transpose tiles, one tile per 256-thread block (4 waves cooperate)
#define FT_TILES  ((FT_OUT / 64) * (NFEAT / 64))    // 5120
#define FFT_TILES ((FT_OUT / 64) * (NVFEAT / 64))   // 80
#define NTILES    (FT_TILES + FFT_TILES)            // 5200

typedef float v4f __attribute__((ext_vector_type(4)));   // clang-native vec4

// pack two f32 into one u32 of 2 bf16 (RNE)
__device__ inline unsigned int bpack(float a, float b) {
    unsigned int ua = __float_as_uint(a), ub = __float_as_uint(b);
    ua = (ua + 0x7fff + ((ua >> 16) & 1)) >> 16;
    ub = (ub + 0x7fff + ((ub >> 16) & 1)) >> 16;
    return ua | (ub << 16);
}
__device__ inline float bf2f(unsigned int u) {        // low 16 bits -> f32
    return __uint_as_float(u << 16);
}
__device__ inline float bf2f_hi(unsigned int u) {     // high 16 bits -> f32
    return __uint_as_float(u & 0xffff0000u);
}

// ---------------------------------------------------------------------------
// K1: transpose + pack. W[F][C] f32 row-major -> T[C][F] bf16 row-major.
// 64x64 tile per block (proven R6). ft_w reads are nontemporal (read-once):
// keep L2/L3 for the ftT the gather kernel immediately re-reads.
__global__ __launch_bounds__(256) void transpose_pack(
    const float* __restrict__ ft_w, const float* __restrict__ fft_w,
    unsigned short* __restrict__ ftT, unsigned short* __restrict__ fftT)
{
    __shared__ float tile[64][65];   // 16.64 KB, stored transposed: tile[c][f]
    const int wid  = threadIdx.x >> 6;
    const int lane = threadIdx.x & 63;
    const int t = blockIdx.x;

    const float* W; unsigned short* T; int C, fb, cb;
    if (t < FT_TILES) {
        W = ft_w;  T = ftT;  C = NFEAT;
        fb = (t & 7) * 64;  cb = (t >> 3) * 64;
    } else {
        int u = t - FT_TILES;
        W = fft_w; T = fftT; C = NVFEAT;
        fb = (u & 7) * 64;  cb = (u >> 3) * 64;
    }

    // read 64 f-rows x 64 c (256B contiguous per 16-lane group), nontemporal
#pragma unroll
    for (int it = 0; it < 4; ++it) {
        const int row = it * 16 + wid * 4 + (lane >> 4);   // 0..63 unique
        const int cq  = (lane & 15) * 4;                   // 16 lanes = 256B
        const v4f v = __builtin_nontemporal_load(
            (const v4f*)(W + (size_t)(fb + row) * C + cb + cq));
        tile[cq + 0][row] = v.x;
        tile[cq + 1][row] = v.y;
        tile[cq + 2][row] = v.z;
        tile[cq + 3][row] = v.w;
    }
    __syncthreads();

    // write 64 c-rows x 64 f bf16 (128B per row = full line: 8 lanes x 16B)
#pragma unroll
    for (int it = 0; it < 2; ++it) {
        const int c  = it * 32 + (threadIdx.x >> 3);       // 0..63
        const int f0 = (threadIdx.x & 7) * 8;              // 0..56
        uint4 o;
        unsigned int* op = (unsigned int*)&o;
#pragma unroll
        for (int j = 0; j < 4; ++j)
            op[j] = bpack(tile[c][f0 + 2 * j], tile[c][f0 + 2 * j + 1]);
        *(uint4*)(T + (size_t)(cb + c) * FT_OUT + fb + f0) = o;
    }
}

// ---------------------------------------------------------------------------
// K2: fused gather + finalize, wave-per-entry (proven R5/R6), with the
// 15-iteration entry loop fully unrolled so all independent uint4 row-gathers
// issue up-front (latency-bound phase, not BW-bound).
__global__ __launch_bounds__(512) void gather_out(
    const unsigned short* __restrict__ ftT,   // [NFEAT][FT_OUT] bf16
    const unsigned short* __restrict__ fftT,  // [NVFEAT][FT_OUT] bf16
    const int*   __restrict__ stm_idx,        // [2][NNZT]
    const int*   __restrict__ nstm_idx,
    const float* __restrict__ values,         // [NNZT]
    const float* __restrict__ ft_b, const float* __restrict__ fft_b,
    const float* __restrict__ out_w, const float* __restrict__ out_b,
    float*       __restrict__ out)
{
    __shared__ int   cs[2][FEATS];
    __shared__ float vs[FEATS];
    __shared__ float pacc[8][2][FT_OUT];      // 32 KB staged partials
    __shared__ float red[8];

    const int b    = blockIdx.x;
    const int wid  = threadIdx.x >> 6;
    const int lane = threadIdx.x & 63;

    if (threadIdx.x < FEATS)
        cs[0][threadIdx.x] = stm_idx[NNZT + b * FEATS + threadIdx.x];
    else if (threadIdx.x < 2 * FEATS)
        cs[1][threadIdx.x - FEATS] = nstm_idx[NNZT + b * FEATS + (threadIdx.x - FEATS)];
    else if (threadIdx.x < 3 * FEATS)
        vs[threadIdx.x - 2 * FEATS] = values[b * FEATS + (threadIdx.x - 2 * FEATS)];
    __syncthreads();

    const int f0 = lane * 8;
    float a0[8], a1[8];
#pragma unroll
    for (int i = 0; i < 8; ++i) { a0[i] = 0.0f; a1[i] = 0.0f; }

    // 120 virtual entries: k = h*60 + j; j<30 -> ftT[c], j>=30 -> fftT[c%640].
    // Wave w takes k = w, w+8, ... (15 iterations, fully unrolled).
#pragma unroll
    for (int i = 0; i < 15; ++i) {
        const int k = wid + 8 * i;
        const int h = k >= 2 * FEATS;
        const int j = k - h * 2 * FEATS;          // 0..59
        const int jj = (j >= FEATS) ? j - FEATS : j;
        const int c = cs[h][jj];
        const float v = vs[jj];
        const unsigned short* rowp = (j >= FEATS)
            ? fftT + (size_t)(c % NVFEAT) * FT_OUT
            : ftT  + (size_t)c * FT_OUT;
        const uint4 r = *(const uint4*)(rowp + f0);
        const unsigned int* rw = (const unsigned int*)&r;
        float* acc = h ? a1 : a0;
#pragma unroll
        for (int q = 0; q < 4; ++q) {
            acc[2 * q]     += bf2f(rw[q]) * v;
            acc[2 * q + 1] += bf2f_hi(rw[q]) * v;
        }
    }

#pragma unroll
    for (int i = 0; i < 8; i += 4) {
        *(float4*)&pacc[wid][0][f0 + i] = make_float4(a0[i], a0[i+1], a0[i+2], a0[i+3]);
        *(float4*)&pacc[wid][1][f0 + i] = make_float4(a1[i], a1[i+1], a1[i+2], a1[i+3]);
    }
    __syncthreads();

    const int f = threadIdx.x;
    float s0 = 0.0f, s1 = 0.0f;
#pragma unroll
    for (int w = 0; w < 8; ++w) { s0 += pacc[w][0][f]; s1 += pacc[w][1][f]; }

    const float bias = ft_b[f] + fft_b[f];
    const float h0 = fminf(fmaxf(s0 + bias, 0.0f), 1.0f);
    const float h1 = fminf(fmaxf(s1 + bias, 0.0f), 1.0f);

    float total = h0 * out_w[f] + h1 * out_w[FT_OUT + f];
#pragma unroll
    for (int off = 32; off > 0; off >>= 1)
        total += __shfl_down(total, off, 64);
    if (lane == 0) red[wid] = total;
    __syncthreads();
    if (threadIdx.x == 0) {
        float s = red[0];
#pragma unroll
        for (int w = 1; w < 8; ++w) s += red[w];
        s += out_b[0];
        out[b] = 1.0f / (1.0f + expf(-s));
    }
}

// ---------------------------------------------------------------------------
// Fallback (ws too small): proven round-1 direct kernel (slow but correct).
__global__ __launch_bounds__(512) void halfkp_direct(
    const int* __restrict__ stm_idx, const int* __restrict__ nstm_idx,
    const float* __restrict__ values,
    const float* __restrict__ ft_w, const float* __restrict__ ft_b,
    const float* __restrict__ fft_w, const float* __restrict__ fft_b,
    const float* __restrict__ out_w, const float* __restrict__ out_b,
    float* __restrict__ out)
{
    const int b = blockIdx.x;
    const int f = threadIdx.x;
    const float bias = ft_b[f] + fft_b[f];
    const float* ftrow  = ft_w  + (size_t)f * NFEAT;
    const float* fftrow = fft_w + f * NVFEAT;
    float acc0 = bias, acc1 = bias;
    for (int k = 0; k < FEATS; ++k) {
        int j = b * FEATS + k;
        int c0 = stm_idx[NNZT + j], c1 = nstm_idx[NNZT + j];
        float v = values[j];
        acc0 += (ftrow[c0] + fftrow[c0 % NVFEAT]) * v;
        acc1 += (ftrow[c1] + fftrow[c1 % NVFEAT]) * v;
    }
    const float h0 = fminf(fmaxf(acc0, 0.0f), 1.0f);
    const float h1 = fminf(fmaxf(acc1, 0.0f), 1.0f);
    float total = h0 * out_w[f] + h1 * out_w[FT_OUT + f];
#pragma unroll
    for (int off = 32; off > 0; off >>= 1)
        total += __shfl_down(total, off, 64);
    __shared__ float red[8];
    if ((threadIdx.x & 63) == 0) red[threadIdx.x >> 6] = total;
    __syncthreads();
    if (threadIdx.x == 0) {
        float s = red[0];
#pragma unroll
        for (int w = 1; w < 8; ++w) s += red[w];
        out[b] = 1.0f / (1.0f + expf(-(s + out_b[0])));
    }
}

// ---------------------------------------------------------------------------
extern "C" void kernel_launch(void* const* d_in, const int* in_sizes, int n_in,
                              void* d_out, int out_size, void* d_ws, size_t ws_size,
                              hipStream_t stream)
{
    const int*   stm_idx  = (const int*)  d_in[0];
    const int*   nstm_idx = (const int*)  d_in[1];
    const float* values   = (const float*)d_in[2];
    const float* ft_w     = (const float*)d_in[3];
    const float* ft_b     = (const float*)d_in[4];
    const float* fft_w    = (const float*)d_in[5];
    const float* fft_b    = (const float*)d_in[6];
    const float* out_w    = (const float*)d_in[7];
    const float* out_b    = (const float*)d_in[8];
    float*       out      = (float*)d_out;

    const size_t ftT_bytes  = (size_t)NFEAT  * FT_OUT * 2;
    const size_t fftT_bytes = (size_t)NVFEAT * FT_OUT * 2;

    if (ws_size >= ftT_bytes + fftT_bytes) {
        unsigned short* ftT  = (unsigned short*)d_ws;
        unsigned short* fftT = (unsigned short*)((char*)d_ws + ftT_bytes);

        transpose_pack<<<NTILES, 256, 0, stream>>>(ft_w, fft_w, ftT, fftT);
        gather_out<<<BATCH, 512, 0, stream>>>(ftT, fftT, stm_idx, nstm_idx,
                                              values, ft_b, fft_b, out_w, out_b, out);
    } else {
        halfkp_direct<<<BATCH, 512, 0, stream>>>(stm_idx, nstm_idx, values,
                                                 ft_w, ft_b, fft_w, fft_b,
                                                 out_w, out_b, out);
    }
}